// Round 1
// baseline (580.334 us; speedup 1.0000x reference)
//
#include <hip/hip_runtime.h>
#include <hip/hip_bf16.h>

// GCN forward: 3 layers, N=100000, HIDDEN=128, E=600000.
// Strategy: aggregation is linear => compute A_norm * x first, then GEMM by W.
// CSR (pull) aggregation built once per launch via counting sort; no per-layer atomics.

#define HID 128

// ---------- preprocessing ----------

__global__ void k_init_cnt(int* cnt, int n) {
    int i = blockIdx.x * blockDim.x + threadIdx.x;
    if (i < n) cnt[i] = 1;  // self-loop
}

__global__ void k_count_edges(const int* __restrict__ ei, int* cnt, int E) {
    int e = blockIdx.x * blockDim.x + threadIdx.x;
    if (e < E) atomicAdd(&cnt[ei[E + e]], 1);   // dst = ei[E+e]
}

// chunk sums: CHUNK=1024 (256 thr x 4)
__global__ void k_scanA(const int* __restrict__ cnt, int* csum, int n) {
    __shared__ int sd[256];
    int t = threadIdx.x;
    int base = blockIdx.x * 1024 + t * 4;
    int s = 0;
#pragma unroll
    for (int j = 0; j < 4; j++) { int i = base + j; if (i < n) s += cnt[i]; }
    sd[t] = s; __syncthreads();
    for (int off = 128; off > 0; off >>= 1) {
        if (t < off) sd[t] += sd[t + off];
        __syncthreads();
    }
    if (t == 0) csum[blockIdx.x] = sd[0];
}

__global__ void k_scanB(int* csum, int* offsets, int nchunk, int n) {
    if (threadIdx.x == 0 && blockIdx.x == 0) {
        int run = 0;
        for (int b = 0; b < nchunk; b++) { int v = csum[b]; csum[b] = run; run += v; }
        offsets[n] = run;   // total = E + N
    }
}

__global__ void k_scanC(const int* __restrict__ cnt, const int* __restrict__ csum,
                        int* offsets, int n) {
    __shared__ int sd[256];
    int t = threadIdx.x;
    int base = blockIdx.x * 1024 + t * 4;
    int c[4]; int s = 0;
#pragma unroll
    for (int j = 0; j < 4; j++) {
        c[j] = (base + j < n) ? cnt[base + j] : 0;
        s += c[j];
    }
    sd[t] = s; __syncthreads();
    // inclusive Hillis-Steele over 256 thread sums
    for (int off = 1; off < 256; off <<= 1) {
        int v = (t >= off) ? sd[t - off] : 0;
        __syncthreads();
        sd[t] += v;
        __syncthreads();
    }
    int run = sd[t] - s + csum[blockIdx.x];  // exclusive prefix + chunk base
#pragma unroll
    for (int j = 0; j < 4; j++) {
        if (base + j < n) offsets[base + j] = run;
        run += c[j];
    }
}

__global__ void k_node_init(const int* __restrict__ cnt, const int* __restrict__ offsets,
                            int* cursor, float* dinv, int* adj_src, float* adj_norm, int n) {
    int i = blockIdx.x * blockDim.x + threadIdx.x;
    if (i >= n) return;
    float di = rsqrtf((float)cnt[i]);   // deg >= 1 always (self-loop)
    dinv[i] = di;
    int o = offsets[i];
    cursor[i] = o + 1;
    adj_src[o] = i;        // self-loop entry first
    adj_norm[o] = di * di;
}

__global__ void k_fill_edges(const int* __restrict__ ei, int* cursor,
                             const float* __restrict__ dinv,
                             int* adj_src, float* adj_norm, int E) {
    int e = blockIdx.x * blockDim.x + threadIdx.x;
    if (e >= E) return;
    int s = ei[e];
    int d = ei[E + e];
    int pos = atomicAdd(&cursor[d], 1);
    adj_src[pos] = s;
    adj_norm[pos] = dinv[s] * dinv[d];
}

// ---------- per-layer: pull aggregation (one wave per node) ----------

__global__ __launch_bounds__(256) void k_agg(const float* __restrict__ x,
                                             const int* __restrict__ offsets,
                                             const int* __restrict__ adj_src,
                                             const float* __restrict__ adj_norm,
                                             float* __restrict__ out, int n) {
    int gid = blockIdx.x * blockDim.x + threadIdx.x;
    int node = gid >> 6;
    int lane = gid & 63;
    if (node >= n) return;
    int beg = offsets[node];
    int end = offsets[node + 1];
    float2 acc = {0.f, 0.f};
    for (int e = beg; e < end; e++) {
        int s = adj_src[e];          // wave-uniform (broadcast load)
        float w = adj_norm[e];
        float2 v = ((const float2*)(x + (size_t)s * HID))[lane];
        acc.x += w * v.x;
        acc.y += w * v.y;
    }
    ((float2*)(out + (size_t)node * HID))[lane] = acc;
}

// ---------- per-layer: GEMM (N x 128) @ (128 x 128) + bias + relu ----------
// W fully in LDS (64KB) + 32-row x tile (16KB) => 80KB => 2 blocks/CU.

__global__ __launch_bounds__(256, 2) void k_gemm_bias_relu(const float* __restrict__ A,
                                                           const float* __restrict__ W,
                                                           const float* __restrict__ bias,
                                                           float* __restrict__ out,
                                                           int nrows) {
    __shared__ float Wl[HID * HID];   // 64 KB, [k][f]
    __shared__ float Xs[32 * HID];    // 16 KB, [row][k]
    int t = threadIdx.x;

    {   // stage W once per block
        const float4* Wg = (const float4*)W;
        float4* Wd = (float4*)Wl;
        for (int i = t; i < (HID * HID) / 4; i += 256) Wd[i] = Wg[i];
    }

    int tx = t & 31;   // feat group: f0 = tx*4
    int ty = t >> 5;   // row group:  r0 = ty*4
    int ntiles = nrows / 32;   // 100000 % 32 == 0

    for (int tile = blockIdx.x; tile < ntiles; tile += gridDim.x) {
        __syncthreads();   // protect Xs (and W on first iter)
        const float4* Ag = (const float4*)(A + (size_t)tile * 32 * HID);
        float4* Xd = (float4*)Xs;
#pragma unroll
        for (int i = 0; i < 4; i++) Xd[t + i * 256] = Ag[t + i * 256];
        __syncthreads();

        float acc[4][4] = {};
#pragma unroll 8
        for (int k = 0; k < HID; k++) {
            float4 wv = ((const float4*)(Wl + k * HID))[tx];
#pragma unroll
            for (int r = 0; r < 4; r++) {
                float xr = Xs[(ty * 4 + r) * HID + k];
                acc[r][0] += xr * wv.x;
                acc[r][1] += xr * wv.y;
                acc[r][2] += xr * wv.z;
                acc[r][3] += xr * wv.w;
            }
        }

        float4 bb = ((const float4*)bias)[tx];
#pragma unroll
        for (int r = 0; r < 4; r++) {
            float4 v;
            v.x = fmaxf(acc[r][0] + bb.x, 0.f);
            v.y = fmaxf(acc[r][1] + bb.y, 0.f);
            v.z = fmaxf(acc[r][2] + bb.z, 0.f);
            v.w = fmaxf(acc[r][3] + bb.w, 0.f);
            ((float4*)(out + (size_t)(tile * 32 + ty * 4 + r) * HID))[tx] = v;
        }
    }
}

// ---------- launch ----------

extern "C" void kernel_launch(void* const* d_in, const int* in_sizes, int n_in,
                              void* d_out, int out_size, void* d_ws, size_t ws_size,
                              hipStream_t stream) {
    const int* ei = (const int*)d_in[0];          // (2, E) int32
    const float* emb = (const float*)d_in[1];     // (N, 128)
    const float* Ws = (const float*)d_in[2];      // (3, 128, 128)
    const float* bs = (const float*)d_in[3];      // (3, 128)

    const int E = in_sizes[0] / 2;                // 600000
    const int N = in_sizes[1] / HID;              // 100000
    const int NL = in_sizes[3] / HID;             // 3
    const int TOT = E + N;

    // workspace carve-up (256B aligned)
    char* p = (char*)d_ws;
    auto carve = [&](size_t bytes) {
        char* r = p;
        p += (bytes + 255) & ~(size_t)255;
        return (void*)r;
    };
    int*   cnt      = (int*)  carve((size_t)N * 4);
    int*   offsets  = (int*)  carve((size_t)(N + 1) * 4);
    int*   cursor   = (int*)  carve((size_t)N * 4);
    float* dinv     = (float*)carve((size_t)N * 4);
    int*   csum     = (int*)  carve(1024 * 4);
    int*   adj_src  = (int*)  carve((size_t)TOT * 4);
    float* adj_norm = (float*)carve((size_t)TOT * 4);
    float* aggbuf   = (float*)carve((size_t)N * HID * 4);
    float* xbuf     = (float*)d_out;   // ping-pong through d_out

    const int NCHUNK = (N + 1023) / 1024;

    k_init_cnt<<<(N + 255) / 256, 256, 0, stream>>>(cnt, N);
    k_count_edges<<<(E + 255) / 256, 256, 0, stream>>>(ei, cnt, E);
    k_scanA<<<NCHUNK, 256, 0, stream>>>(cnt, csum, N);
    k_scanB<<<1, 64, 0, stream>>>(csum, offsets, NCHUNK, N);
    k_scanC<<<NCHUNK, 256, 0, stream>>>(cnt, csum, offsets, N);
    k_node_init<<<(N + 255) / 256, 256, 0, stream>>>(cnt, offsets, cursor, dinv,
                                                     adj_src, adj_norm, N);
    k_fill_edges<<<(E + 255) / 256, 256, 0, stream>>>(ei, cursor, dinv,
                                                      adj_src, adj_norm, E);

    const int aggBlocks = (N * 64 + 255) / 256;
    const float* x = emb;
    for (int l = 0; l < NL; l++) {
        k_agg<<<aggBlocks, 256, 0, stream>>>(x, offsets, adj_src, adj_norm, aggbuf, N);
        k_gemm_bias_relu<<<512, 256, 0, stream>>>(aggbuf, Ws + (size_t)l * HID * HID,
                                                  bs + (size_t)l * HID, xbuf, N);
        x = xbuf;
    }
}

// Round 6
// 579.854 us; speedup vs baseline: 1.0008x; 1.0008x over previous
//
#include <hip/hip_runtime.h>
#include <hip/hip_bf16.h>

// GCN forward: 3 layers, N=100000, HIDDEN=128, E=600000.
// Strategy: aggregation is linear => compute A_norm * x first, then GEMM by W.
// CSR (pull) aggregation built once per launch via counting sort; no per-layer atomics.
// ROUND-5 CONTROL: byte-identical resubmission of the round-1 source that passed
// at 580 us, to disambiguate broker infra flake (rounds 2-5) from source-triggered
// container failure.

#define HID 128

// ---------- preprocessing ----------

__global__ void k_init_cnt(int* cnt, int n) {
    int i = blockIdx.x * blockDim.x + threadIdx.x;
    if (i < n) cnt[i] = 1;  // self-loop
}

__global__ void k_count_edges(const int* __restrict__ ei, int* cnt, int E) {
    int e = blockIdx.x * blockDim.x + threadIdx.x;
    if (e < E) atomicAdd(&cnt[ei[E + e]], 1);   // dst = ei[E+e]
}

// chunk sums: CHUNK=1024 (256 thr x 4)
__global__ void k_scanA(const int* __restrict__ cnt, int* csum, int n) {
    __shared__ int sd[256];
    int t = threadIdx.x;
    int base = blockIdx.x * 1024 + t * 4;
    int s = 0;
#pragma unroll
    for (int j = 0; j < 4; j++) { int i = base + j; if (i < n) s += cnt[i]; }
    sd[t] = s; __syncthreads();
    for (int off = 128; off > 0; off >>= 1) {
        if (t < off) sd[t] += sd[t + off];
        __syncthreads();
    }
    if (t == 0) csum[blockIdx.x] = sd[0];
}

__global__ void k_scanB(int* csum, int* offsets, int nchunk, int n) {
    if (threadIdx.x == 0 && blockIdx.x == 0) {
        int run = 0;
        for (int b = 0; b < nchunk; b++) { int v = csum[b]; csum[b] = run; run += v; }
        offsets[n] = run;   // total = E + N
    }
}

__global__ void k_scanC(const int* __restrict__ cnt, const int* __restrict__ csum,
                        int* offsets, int n) {
    __shared__ int sd[256];
    int t = threadIdx.x;
    int base = blockIdx.x * 1024 + t * 4;
    int c[4]; int s = 0;
#pragma unroll
    for (int j = 0; j < 4; j++) {
        c[j] = (base + j < n) ? cnt[base + j] : 0;
        s += c[j];
    }
    sd[t] = s; __syncthreads();
    // inclusive Hillis-Steele over 256 thread sums
    for (int off = 1; off < 256; off <<= 1) {
        int v = (t >= off) ? sd[t - off] : 0;
        __syncthreads();
        sd[t] += v;
        __syncthreads();
    }
    int run = sd[t] - s + csum[blockIdx.x];  // exclusive prefix + chunk base
#pragma unroll
    for (int j = 0; j < 4; j++) {
        if (base + j < n) offsets[base + j] = run;
        run += c[j];
    }
}

__global__ void k_node_init(const int* __restrict__ cnt, const int* __restrict__ offsets,
                            int* cursor, float* dinv, int* adj_src, float* adj_norm, int n) {
    int i = blockIdx.x * blockDim.x + threadIdx.x;
    if (i >= n) return;
    float di = rsqrtf((float)cnt[i]);   // deg >= 1 always (self-loop)
    dinv[i] = di;
    int o = offsets[i];
    cursor[i] = o + 1;
    adj_src[o] = i;        // self-loop entry first
    adj_norm[o] = di * di;
}

__global__ void k_fill_edges(const int* __restrict__ ei, int* cursor,
                             const float* __restrict__ dinv,
                             int* adj_src, float* adj_norm, int E) {
    int e = blockIdx.x * blockDim.x + threadIdx.x;
    if (e >= E) return;
    int s = ei[e];
    int d = ei[E + e];
    int pos = atomicAdd(&cursor[d], 1);
    adj_src[pos] = s;
    adj_norm[pos] = dinv[s] * dinv[d];
}

// ---------- per-layer: pull aggregation (one wave per node) ----------

__global__ __launch_bounds__(256) void k_agg(const float* __restrict__ x,
                                             const int* __restrict__ offsets,
                                             const int* __restrict__ adj_src,
                                             const float* __restrict__ adj_norm,
                                             float* __restrict__ out, int n) {
    int gid = blockIdx.x * blockDim.x + threadIdx.x;
    int node = gid >> 6;
    int lane = gid & 63;
    if (node >= n) return;
    int beg = offsets[node];
    int end = offsets[node + 1];
    float2 acc = {0.f, 0.f};
    for (int e = beg; e < end; e++) {
        int s = adj_src[e];          // wave-uniform (broadcast load)
        float w = adj_norm[e];
        float2 v = ((const float2*)(x + (size_t)s * HID))[lane];
        acc.x += w * v.x;
        acc.y += w * v.y;
    }
    ((float2*)(out + (size_t)node * HID))[lane] = acc;
}

// ---------- per-layer: GEMM (N x 128) @ (128 x 128) + bias + relu ----------
// W fully in LDS (64KB) + 32-row x tile (16KB) => 80KB => 2 blocks/CU.

__global__ __launch_bounds__(256, 2) void k_gemm_bias_relu(const float* __restrict__ A,
                                                           const float* __restrict__ W,
                                                           const float* __restrict__ bias,
                                                           float* __restrict__ out,
                                                           int nrows) {
    __shared__ float Wl[HID * HID];   // 64 KB, [k][f]
    __shared__ float Xs[32 * HID];    // 16 KB, [row][k]
    int t = threadIdx.x;

    {   // stage W once per block
        const float4* Wg = (const float4*)W;
        float4* Wd = (float4*)Wl;
        for (int i = t; i < (HID * HID) / 4; i += 256) Wd[i] = Wg[i];
    }

    int tx = t & 31;   // feat group: f0 = tx*4
    int ty = t >> 5;   // row group:  r0 = ty*4
    int ntiles = nrows / 32;   // 100000 % 32 == 0

    for (int tile = blockIdx.x; tile < ntiles; tile += gridDim.x) {
        __syncthreads();   // protect Xs (and W on first iter)
        const float4* Ag = (const float4*)(A + (size_t)tile * 32 * HID);
        float4* Xd = (float4*)Xs;
#pragma unroll
        for (int i = 0; i < 4; i++) Xd[t + i * 256] = Ag[t + i * 256];
        __syncthreads();

        float acc[4][4] = {};
#pragma unroll 8
        for (int k = 0; k < HID; k++) {
            float4 wv = ((const float4*)(Wl + k * HID))[tx];
#pragma unroll
            for (int r = 0; r < 4; r++) {
                float xr = Xs[(ty * 4 + r) * HID + k];
                acc[r][0] += xr * wv.x;
                acc[r][1] += xr * wv.y;
                acc[r][2] += xr * wv.z;
                acc[r][3] += xr * wv.w;
            }
        }

        float4 bb = ((const float4*)bias)[tx];
#pragma unroll
        for (int r = 0; r < 4; r++) {
            float4 v;
            v.x = fmaxf(acc[r][0] + bb.x, 0.f);
            v.y = fmaxf(acc[r][1] + bb.y, 0.f);
            v.z = fmaxf(acc[r][2] + bb.z, 0.f);
            v.w = fmaxf(acc[r][3] + bb.w, 0.f);
            ((float4*)(out + (size_t)(tile * 32 + ty * 4 + r) * HID))[tx] = v;
        }
    }
}

// ---------- launch ----------

extern "C" void kernel_launch(void* const* d_in, const int* in_sizes, int n_in,
                              void* d_out, int out_size, void* d_ws, size_t ws_size,
                              hipStream_t stream) {
    const int* ei = (const int*)d_in[0];          // (2, E) int32
    const float* emb = (const float*)d_in[1];     // (N, 128)
    const float* Ws = (const float*)d_in[2];      // (3, 128, 128)
    const float* bs = (const float*)d_in[3];      // (3, 128)

    const int E = in_sizes[0] / 2;                // 600000
    const int N = in_sizes[1] / HID;              // 100000
    const int NL = in_sizes[3] / HID;             // 3
    const int TOT = E + N;

    // workspace carve-up (256B aligned)
    char* p = (char*)d_ws;
    auto carve = [&](size_t bytes) {
        char* r = p;
        p += (bytes + 255) & ~(size_t)255;
        return (void*)r;
    };
    int*   cnt      = (int*)  carve((size_t)N * 4);
    int*   offsets  = (int*)  carve((size_t)(N + 1) * 4);
    int*   cursor   = (int*)  carve((size_t)N * 4);
    float* dinv     = (float*)carve((size_t)N * 4);
    int*   csum     = (int*)  carve(1024 * 4);
    int*   adj_src  = (int*)  carve((size_t)TOT * 4);
    float* adj_norm = (float*)carve((size_t)TOT * 4);
    float* aggbuf   = (float*)carve((size_t)N * HID * 4);
    float* xbuf     = (float*)d_out;   // ping-pong through d_out

    const int NCHUNK = (N + 1023) / 1024;

    k_init_cnt<<<(N + 255) / 256, 256, 0, stream>>>(cnt, N);
    k_count_edges<<<(E + 255) / 256, 256, 0, stream>>>(ei, cnt, E);
    k_scanA<<<NCHUNK, 256, 0, stream>>>(cnt, csum, N);
    k_scanB<<<1, 64, 0, stream>>>(csum, offsets, NCHUNK, N);
    k_scanC<<<NCHUNK, 256, 0, stream>>>(cnt, csum, offsets, N);
    k_node_init<<<(N + 255) / 256, 256, 0, stream>>>(cnt, offsets, cursor, dinv,
                                                     adj_src, adj_norm, N);
    k_fill_edges<<<(E + 255) / 256, 256, 0, stream>>>(ei, cursor, dinv,
                                                      adj_src, adj_norm, E);

    const int aggBlocks = (N * 64 + 255) / 256;
    const float* x = emb;
    for (int l = 0; l < NL; l++) {
        k_agg<<<aggBlocks, 256, 0, stream>>>(x, offsets, adj_src, adj_norm, aggbuf, N);
        k_gemm_bias_relu<<<512, 256, 0, stream>>>(aggbuf, Ws + (size_t)l * HID * HID,
                                                  bs + (size_t)l * HID, xbuf, N);
        x = xbuf;
    }
}

// Round 8
// 520.142 us; speedup vs baseline: 1.1157x; 1.1148x over previous
//
#include <hip/hip_runtime.h>
#include <hip/hip_bf16.h>

// GCN forward: 3 layers, N=100000, HIDDEN=128, E=600000.
// Strategy: aggregation is linear => compute A_norm * x first, then GEMM by W.
// CSR (pull) aggregation built once per launch via counting sort; no per-layer atomics.
// NOTE: manual batch-4 unrolled k_agg loops kill the bench container (5/5 failures,
// source-correlated; rounds 2-7). This round keeps ONE x-row load per loop iteration
// (like the passing round-1 kernel) but remaps lanes so that single load instruction
// covers TWO edges: wave quarters = (edge parity, feature half), float4 per lane,
// __shfl_xor(32) combine. Halves per-edge latency chain without the cursed shape.

#define HID 128

// ---------- preprocessing ----------

__global__ void k_init_cnt(int* cnt, int n) {
    int i = blockIdx.x * blockDim.x + threadIdx.x;
    if (i < n) cnt[i] = 1;  // self-loop
}

__global__ void k_count_edges(const int* __restrict__ ei, int* cnt, int E) {
    int e = blockIdx.x * blockDim.x + threadIdx.x;
    if (e < E) atomicAdd(&cnt[ei[E + e]], 1);   // dst = ei[E+e]
}

// chunk sums: CHUNK=1024 (256 thr x 4)
__global__ void k_scanA(const int* __restrict__ cnt, int* csum, int n) {
    __shared__ int sd[256];
    int t = threadIdx.x;
    int base = blockIdx.x * 1024 + t * 4;
    int s = 0;
#pragma unroll
    for (int j = 0; j < 4; j++) { int i = base + j; if (i < n) s += cnt[i]; }
    sd[t] = s; __syncthreads();
    for (int off = 128; off > 0; off >>= 1) {
        if (t < off) sd[t] += sd[t + off];
        __syncthreads();
    }
    if (t == 0) csum[blockIdx.x] = sd[0];
}

__global__ void k_scanB(int* csum, int* offsets, int nchunk, int n) {
    if (threadIdx.x == 0 && blockIdx.x == 0) {
        int run = 0;
        for (int b = 0; b < nchunk; b++) { int v = csum[b]; csum[b] = run; run += v; }
        offsets[n] = run;   // total = E + N
    }
}

__global__ void k_scanC(const int* __restrict__ cnt, const int* __restrict__ csum,
                        int* offsets, int n) {
    __shared__ int sd[256];
    int t = threadIdx.x;
    int base = blockIdx.x * 1024 + t * 4;
    int c[4]; int s = 0;
#pragma unroll
    for (int j = 0; j < 4; j++) {
        c[j] = (base + j < n) ? cnt[base + j] : 0;
        s += c[j];
    }
    sd[t] = s; __syncthreads();
    // inclusive Hillis-Steele over 256 thread sums
    for (int off = 1; off < 256; off <<= 1) {
        int v = (t >= off) ? sd[t - off] : 0;
        __syncthreads();
        sd[t] += v;
        __syncthreads();
    }
    int run = sd[t] - s + csum[blockIdx.x];  // exclusive prefix + chunk base
#pragma unroll
    for (int j = 0; j < 4; j++) {
        if (base + j < n) offsets[base + j] = run;
        run += c[j];
    }
}

__global__ void k_node_init(const int* __restrict__ cnt, const int* __restrict__ offsets,
                            int* cursor, float* dinv, int* adj_src, float* adj_norm, int n) {
    int i = blockIdx.x * blockDim.x + threadIdx.x;
    if (i >= n) return;
    float di = rsqrtf((float)cnt[i]);   // deg >= 1 always (self-loop)
    dinv[i] = di;
    int o = offsets[i];
    cursor[i] = o + 1;
    adj_src[o] = i;        // self-loop entry first
    adj_norm[o] = di * di;
}

__global__ void k_fill_edges(const int* __restrict__ ei, int* cursor,
                             const float* __restrict__ dinv,
                             int* adj_src, float* adj_norm, int E) {
    int e = blockIdx.x * blockDim.x + threadIdx.x;
    if (e >= E) return;
    int s = ei[e];
    int d = ei[E + e];
    int pos = atomicAdd(&cursor[d], 1);
    adj_src[pos] = s;
    adj_norm[pos] = dinv[s] * dinv[d];
}

// ---------- per-layer: pull aggregation ----------
// One wave per node. Wave quarters: q>>1 = edge-slot parity, q&1 = feature half.
// Each loop iteration issues ONE float4 row-load instruction that covers 2 edges
// (64 lanes x 16B = 1KB = two 512B rows). Parity partials combined via shfl_xor(32).

__global__ __launch_bounds__(256) void k_agg(const float* __restrict__ x,
                                             const int* __restrict__ offsets,
                                             const int* __restrict__ adj_src,
                                             const float* __restrict__ adj_norm,
                                             float* __restrict__ out, int n) {
    int gid = blockIdx.x * blockDim.x + threadIdx.x;
    int node = gid >> 6;
    int lane = gid & 63;
    if (node >= n) return;
    int beg = offsets[node];
    int end = offsets[node + 1];
    int q    = lane >> 4;            // quarter 0..3
    int ql   = lane & 15;
    int f4   = (q & 1) * 16 + ql;    // float4 index within row, [0,32)
    int epar = q >> 1;               // edge-slot parity 0/1
    float4 acc = {0.f, 0.f, 0.f, 0.f};
    for (int e = beg; e < end; e += 2) {
        int me = e + epar;
        int mc = me < end ? me : end - 1;          // clamp -> always-valid load
        int s  = adj_src[mc];                      // broadcast within quarter-pair
        float w = me < end ? adj_norm[mc] : 0.f;   // masked weight for odd tail
        float4 v = ((const float4*)(x + (size_t)s * HID))[f4];
        acc.x += w * v.x;
        acc.y += w * v.y;
        acc.z += w * v.z;
        acc.w += w * v.w;
    }
    // combine the two edge-parity streams: lane^32 holds same features, other parity
    acc.x += __shfl_xor(acc.x, 32);
    acc.y += __shfl_xor(acc.y, 32);
    acc.z += __shfl_xor(acc.z, 32);
    acc.w += __shfl_xor(acc.w, 32);
    if (lane < 32)
        ((float4*)(out + (size_t)node * HID))[lane] = acc;
}

// ---------- per-layer: GEMM (N x 128) @ (128 x 128) + bias + relu ----------
// W fully in LDS (64KB) + 32-row x tile (16KB) => 80KB => 2 blocks/CU.

__global__ __launch_bounds__(256, 2) void k_gemm_bias_relu(const float* __restrict__ A,
                                                           const float* __restrict__ W,
                                                           const float* __restrict__ bias,
                                                           float* __restrict__ out,
                                                           int nrows) {
    __shared__ float Wl[HID * HID];   // 64 KB, [k][f]
    __shared__ float Xs[32 * HID];    // 16 KB, [row][k]
    int t = threadIdx.x;

    {   // stage W once per block
        const float4* Wg = (const float4*)W;
        float4* Wd = (float4*)Wl;
        for (int i = t; i < (HID * HID) / 4; i += 256) Wd[i] = Wg[i];
    }

    int tx = t & 31;   // feat group: f0 = tx*4
    int ty = t >> 5;   // row group:  r0 = ty*4
    int ntiles = nrows / 32;   // 100000 % 32 == 0

    for (int tile = blockIdx.x; tile < ntiles; tile += gridDim.x) {
        __syncthreads();   // protect Xs (and W on first iter)
        const float4* Ag = (const float4*)(A + (size_t)tile * 32 * HID);
        float4* Xd = (float4*)Xs;
#pragma unroll
        for (int i = 0; i < 4; i++) Xd[t + i * 256] = Ag[t + i * 256];
        __syncthreads();

        float acc[4][4] = {};
#pragma unroll 8
        for (int k = 0; k < HID; k++) {
            float4 wv = ((const float4*)(Wl + k * HID))[tx];
#pragma unroll
            for (int r = 0; r < 4; r++) {
                float xr = Xs[(ty * 4 + r) * HID + k];
                acc[r][0] += xr * wv.x;
                acc[r][1] += xr * wv.y;
                acc[r][2] += xr * wv.z;
                acc[r][3] += xr * wv.w;
            }
        }

        float4 bb = ((const float4*)bias)[tx];
#pragma unroll
        for (int r = 0; r < 4; r++) {
            float4 v;
            v.x = fmaxf(acc[r][0] + bb.x, 0.f);
            v.y = fmaxf(acc[r][1] + bb.y, 0.f);
            v.z = fmaxf(acc[r][2] + bb.z, 0.f);
            v.w = fmaxf(acc[r][3] + bb.w, 0.f);
            ((float4*)(out + (size_t)(tile * 32 + ty * 4 + r) * HID))[tx] = v;
        }
    }
}

// ---------- launch ----------

extern "C" void kernel_launch(void* const* d_in, const int* in_sizes, int n_in,
                              void* d_out, int out_size, void* d_ws, size_t ws_size,
                              hipStream_t stream) {
    const int* ei = (const int*)d_in[0];          // (2, E) int32
    const float* emb = (const float*)d_in[1];     // (N, 128)
    const float* Ws = (const float*)d_in[2];      // (3, 128, 128)
    const float* bs = (const float*)d_in[3];      // (3, 128)

    const int E = in_sizes[0] / 2;                // 600000
    const int N = in_sizes[1] / HID;              // 100000
    const int NL = in_sizes[3] / HID;             // 3
    const int TOT = E + N;

    // workspace carve-up (256B aligned)
    char* p = (char*)d_ws;
    auto carve = [&](size_t bytes) {
        char* r = p;
        p += (bytes + 255) & ~(size_t)255;
        return (void*)r;
    };
    int*   cnt      = (int*)  carve((size_t)N * 4);
    int*   offsets  = (int*)  carve((size_t)(N + 1) * 4);
    int*   cursor   = (int*)  carve((size_t)N * 4);
    float* dinv     = (float*)carve((size_t)N * 4);
    int*   csum     = (int*)  carve(1024 * 4);
    int*   adj_src  = (int*)  carve((size_t)TOT * 4);
    float* adj_norm = (float*)carve((size_t)TOT * 4);
    float* aggbuf   = (float*)carve((size_t)N * HID * 4);
    float* xbuf     = (float*)d_out;   // ping-pong through d_out

    const int NCHUNK = (N + 1023) / 1024;

    k_init_cnt<<<(N + 255) / 256, 256, 0, stream>>>(cnt, N);
    k_count_edges<<<(E + 255) / 256, 256, 0, stream>>>(ei, cnt, E);
    k_scanA<<<NCHUNK, 256, 0, stream>>>(cnt, csum, N);
    k_scanB<<<1, 64, 0, stream>>>(csum, offsets, NCHUNK, N);
    k_scanC<<<NCHUNK, 256, 0, stream>>>(cnt, csum, offsets, N);
    k_node_init<<<(N + 255) / 256, 256, 0, stream>>>(cnt, offsets, cursor, dinv,
                                                     adj_src, adj_norm, N);
    k_fill_edges<<<(E + 255) / 256, 256, 0, stream>>>(ei, cursor, dinv,
                                                      adj_src, adj_norm, E);

    const int aggBlocks = (N * 64 + 255) / 256;
    const float* x = emb;
    for (int l = 0; l < NL; l++) {
        k_agg<<<aggBlocks, 256, 0, stream>>>(x, offsets, adj_src, adj_norm, aggbuf, N);
        k_gemm_bias_relu<<<512, 256, 0, stream>>>(aggbuf, Ws + (size_t)l * HID * HID,
                                                  bs + (size_t)l * HID, xbuf, N);
        x = xbuf;
    }
}

// Round 9
// 502.544 us; speedup vs baseline: 1.1548x; 1.0350x over previous
//
#include <hip/hip_runtime.h>
#include <hip/hip_bf16.h>

// GCN forward: 3 layers, N=100000, HIDDEN=128, E=600000.
// Aggregation is linear => aggregate first (A_norm * x), then GEMM by W.
// CSR (pull) built per launch via counting sort; no per-layer atomics.
// k_agg: wave quarters = (edge parity, feature half); ONE float4 gather per loop
// body covering 2 edges (round-8 passing shape). This round adds #pragma unroll 2
// (compiler-generated MLP; manual multi-gather bodies kill the container, 5/5).
// Also: parallel scanB (was single-thread serial chain) and node_init fused into scanC.

#define HID 128

// ---------- preprocessing ----------

__global__ void k_init_cnt(int* cnt, int n) {
    int i = blockIdx.x * blockDim.x + threadIdx.x;
    if (i < n) cnt[i] = 1;  // self-loop
}

__global__ void k_count_edges(const int* __restrict__ ei, int* cnt, int E) {
    int e = blockIdx.x * blockDim.x + threadIdx.x;
    if (e < E) atomicAdd(&cnt[ei[E + e]], 1);   // dst = ei[E+e]
}

// chunk sums: CHUNK=1024 (256 thr x 4)
__global__ void k_scanA(const int* __restrict__ cnt, int* csum, int n) {
    __shared__ int sd[256];
    int t = threadIdx.x;
    int base = blockIdx.x * 1024 + t * 4;
    int s = 0;
#pragma unroll
    for (int j = 0; j < 4; j++) { int i = base + j; if (i < n) s += cnt[i]; }
    sd[t] = s; __syncthreads();
    for (int off = 128; off > 0; off >>= 1) {
        if (t < off) sd[t] += sd[t + off];
        __syncthreads();
    }
    if (t == 0) csum[blockIdx.x] = sd[0];
}

// parallel exclusive scan over up to 256 chunk sums (NCHUNK=98 here), 1 block
__global__ void k_scanB(int* csum, int* offsets, int nchunk, int n) {
    __shared__ int sd[256];
    int t = threadIdx.x;
    int v = (t < nchunk) ? csum[t] : 0;
    sd[t] = v; __syncthreads();
    for (int off = 1; off < 256; off <<= 1) {
        int u = (t >= off) ? sd[t - off] : 0;
        __syncthreads();
        sd[t] += u;
        __syncthreads();
    }
    if (t < nchunk) csum[t] = sd[t] - v;   // exclusive prefix
    if (t == 0) offsets[n] = sd[255];      // total = E + N
}

// scanC + node_init fused: writes offsets, dinv, cursor, and the self-loop entry.
__global__ void k_scanC(const int* __restrict__ cnt, const int* __restrict__ csum,
                        int* offsets, int* cursor, float* dinv,
                        int* adj_src, float* adj_norm, int n) {
    __shared__ int sd[256];
    int t = threadIdx.x;
    int base = blockIdx.x * 1024 + t * 4;
    int c[4]; int s = 0;
#pragma unroll
    for (int j = 0; j < 4; j++) {
        c[j] = (base + j < n) ? cnt[base + j] : 0;
        s += c[j];
    }
    sd[t] = s; __syncthreads();
    // inclusive Hillis-Steele over 256 thread sums
    for (int off = 1; off < 256; off <<= 1) {
        int v = (t >= off) ? sd[t - off] : 0;
        __syncthreads();
        sd[t] += v;
        __syncthreads();
    }
    int run = sd[t] - s + csum[blockIdx.x];  // exclusive prefix + chunk base
#pragma unroll
    for (int j = 0; j < 4; j++) {
        int i = base + j;
        if (i < n) {
            offsets[i] = run;
            float di = rsqrtf((float)c[j]);   // deg >= 1 (self-loop)
            dinv[i] = di;
            cursor[i] = run + 1;
            adj_src[run] = i;                 // self-loop entry first
            adj_norm[run] = di * di;
        }
        run += c[j];
    }
}

__global__ void k_fill_edges(const int* __restrict__ ei, int* cursor,
                             const float* __restrict__ dinv,
                             int* adj_src, float* adj_norm, int E) {
    int e = blockIdx.x * blockDim.x + threadIdx.x;
    if (e >= E) return;
    int s = ei[e];
    int d = ei[E + e];
    int pos = atomicAdd(&cursor[d], 1);
    adj_src[pos] = s;
    adj_norm[pos] = dinv[s] * dinv[d];
}

// ---------- per-layer: pull aggregation ----------
// One wave per node. Wave quarters: q>>1 = edge-slot parity, q&1 = feature half.
// Each loop body issues ONE float4 row-load covering 2 edges (64 lanes x 16B = 1KB).
// #pragma unroll 2 lets the compiler put 2 gathers in flight (latency-bound chain).

__global__ __launch_bounds__(256) void k_agg(const float* __restrict__ x,
                                             const int* __restrict__ offsets,
                                             const int* __restrict__ adj_src,
                                             const float* __restrict__ adj_norm,
                                             float* __restrict__ out, int n) {
    int gid = blockIdx.x * blockDim.x + threadIdx.x;
    int node = gid >> 6;
    int lane = gid & 63;
    if (node >= n) return;
    int beg = offsets[node];
    int end = offsets[node + 1];
    int q    = lane >> 4;            // quarter 0..3
    int ql   = lane & 15;
    int f4   = (q & 1) * 16 + ql;    // float4 index within row, [0,32)
    int epar = q >> 1;               // edge-slot parity 0/1
    float4 acc = {0.f, 0.f, 0.f, 0.f};
#pragma unroll 2
    for (int e = beg; e < end; e += 2) {
        int me = e + epar;
        int mc = me < end ? me : end - 1;          // clamp -> always-valid load
        int s  = adj_src[mc];                      // broadcast within quarter-pair
        float w = me < end ? adj_norm[mc] : 0.f;   // masked weight for odd tail
        float4 v = ((const float4*)(x + (size_t)s * HID))[f4];
        acc.x += w * v.x;
        acc.y += w * v.y;
        acc.z += w * v.z;
        acc.w += w * v.w;
    }
    // combine the two edge-parity streams: lane^32 holds same features, other parity
    acc.x += __shfl_xor(acc.x, 32);
    acc.y += __shfl_xor(acc.y, 32);
    acc.z += __shfl_xor(acc.z, 32);
    acc.w += __shfl_xor(acc.w, 32);
    if (lane < 32)
        ((float4*)(out + (size_t)node * HID))[lane] = acc;
}

// ---------- per-layer: GEMM (N x 128) @ (128 x 128) + bias + relu ----------
// W fully in LDS (64KB) + 32-row x tile (16KB) => 80KB => 2 blocks/CU.

__global__ __launch_bounds__(256, 2) void k_gemm_bias_relu(const float* __restrict__ A,
                                                           const float* __restrict__ W,
                                                           const float* __restrict__ bias,
                                                           float* __restrict__ out,
                                                           int nrows) {
    __shared__ float Wl[HID * HID];   // 64 KB, [k][f]
    __shared__ float Xs[32 * HID];    // 16 KB, [row][k]
    int t = threadIdx.x;

    {   // stage W once per block
        const float4* Wg = (const float4*)W;
        float4* Wd = (float4*)Wl;
        for (int i = t; i < (HID * HID) / 4; i += 256) Wd[i] = Wg[i];
    }

    int tx = t & 31;   // feat group: f0 = tx*4
    int ty = t >> 5;   // row group:  r0 = ty*4
    int ntiles = nrows / 32;   // 100000 % 32 == 0

    for (int tile = blockIdx.x; tile < ntiles; tile += gridDim.x) {
        __syncthreads();   // protect Xs (and W on first iter)
        const float4* Ag = (const float4*)(A + (size_t)tile * 32 * HID);
        float4* Xd = (float4*)Xs;
#pragma unroll
        for (int i = 0; i < 4; i++) Xd[t + i * 256] = Ag[t + i * 256];
        __syncthreads();

        float acc[4][4] = {};
#pragma unroll 8
        for (int k = 0; k < HID; k++) {
            float4 wv = ((const float4*)(Wl + k * HID))[tx];
#pragma unroll
            for (int r = 0; r < 4; r++) {
                float xr = Xs[(ty * 4 + r) * HID + k];
                acc[r][0] += xr * wv.x;
                acc[r][1] += xr * wv.y;
                acc[r][2] += xr * wv.z;
                acc[r][3] += xr * wv.w;
            }
        }

        float4 bb = ((const float4*)bias)[tx];
#pragma unroll
        for (int r = 0; r < 4; r++) {
            float4 v;
            v.x = fmaxf(acc[r][0] + bb.x, 0.f);
            v.y = fmaxf(acc[r][1] + bb.y, 0.f);
            v.z = fmaxf(acc[r][2] + bb.z, 0.f);
            v.w = fmaxf(acc[r][3] + bb.w, 0.f);
            ((float4*)(out + (size_t)(tile * 32 + ty * 4 + r) * HID))[tx] = v;
        }
    }
}

// ---------- launch ----------

extern "C" void kernel_launch(void* const* d_in, const int* in_sizes, int n_in,
                              void* d_out, int out_size, void* d_ws, size_t ws_size,
                              hipStream_t stream) {
    const int* ei = (const int*)d_in[0];          // (2, E) int32
    const float* emb = (const float*)d_in[1];     // (N, 128)
    const float* Ws = (const float*)d_in[2];      // (3, 128, 128)
    const float* bs = (const float*)d_in[3];      // (3, 128)

    const int E = in_sizes[0] / 2;                // 600000
    const int N = in_sizes[1] / HID;              // 100000
    const int NL = in_sizes[3] / HID;             // 3
    const int TOT = E + N;

    // workspace carve-up (256B aligned)
    char* p = (char*)d_ws;
    auto carve = [&](size_t bytes) {
        char* r = p;
        p += (bytes + 255) & ~(size_t)255;
        return (void*)r;
    };
    int*   cnt      = (int*)  carve((size_t)N * 4);
    int*   offsets  = (int*)  carve((size_t)(N + 1) * 4);
    int*   cursor   = (int*)  carve((size_t)N * 4);
    float* dinv     = (float*)carve((size_t)N * 4);
    int*   csum     = (int*)  carve(1024 * 4);
    int*   adj_src  = (int*)  carve((size_t)TOT * 4);
    float* adj_norm = (float*)carve((size_t)TOT * 4);
    float* aggbuf   = (float*)carve((size_t)N * HID * 4);
    float* xbuf     = (float*)d_out;   // ping-pong through d_out

    const int NCHUNK = (N + 1023) / 1024;   // 98 <= 256 (scanB capacity)

    k_init_cnt<<<(N + 255) / 256, 256, 0, stream>>>(cnt, N);
    k_count_edges<<<(E + 255) / 256, 256, 0, stream>>>(ei, cnt, E);
    k_scanA<<<NCHUNK, 256, 0, stream>>>(cnt, csum, N);
    k_scanB<<<1, 256, 0, stream>>>(csum, offsets, NCHUNK, N);
    k_scanC<<<NCHUNK, 256, 0, stream>>>(cnt, csum, offsets, cursor, dinv,
                                        adj_src, adj_norm, N);
    k_fill_edges<<<(E + 255) / 256, 256, 0, stream>>>(ei, cursor, dinv,
                                                      adj_src, adj_norm, E);

    const int aggBlocks = (N * 64 + 255) / 256;
    const float* x = emb;
    for (int l = 0; l < NL; l++) {
        k_agg<<<aggBlocks, 256, 0, stream>>>(x, offsets, adj_src, adj_norm, aggbuf, N);
        k_gemm_bias_relu<<<512, 256, 0, stream>>>(aggbuf, Ws + (size_t)l * HID * HID,
                                                  bs + (size_t)l * HID, xbuf, N);
        x = xbuf;
    }
}

// Round 10
// 496.755 us; speedup vs baseline: 1.1682x; 1.0117x over previous
//
#include <hip/hip_runtime.h>
#include <hip/hip_bf16.h>

// GCN forward: 3 layers, N=100000, HIDDEN=128, E=600000.
// Aggregation is linear => aggregate first (A_norm * x), then GEMM by W.
// CSR (pull) built per launch via counting sort; no per-layer atomics.
// Round-10: FUSED layer kernel. Agg phase pulls a 32-node tile into LDS
// (round-8/9 verified gather shape: quarters=(edge parity, feature half), ONE
// float4 gather per body, unroll 2), then GEMM phase multiplies by LDS-resident W.
// Kills the aggbuf round-trip (102 MB/layer) and hides GEMM behind gathers.
// Agg phase is HBM/L2-BW bound at ~8.9 B/cy/CU (~90% of m13 ceiling) per round-9.

#define HID 128

// ---------- preprocessing ----------

__global__ void k_init_cnt(int* cnt, int n) {
    int i = blockIdx.x * blockDim.x + threadIdx.x;
    if (i < n) cnt[i] = 1;  // self-loop
}

__global__ void k_count_edges(const int* __restrict__ ei, int* cnt, int E) {
    int e = blockIdx.x * blockDim.x + threadIdx.x;
    if (e < E) atomicAdd(&cnt[ei[E + e]], 1);   // dst = ei[E+e]
}

// chunk sums: CHUNK=1024 (256 thr x 4)
__global__ void k_scanA(const int* __restrict__ cnt, int* csum, int n) {
    __shared__ int sd[256];
    int t = threadIdx.x;
    int base = blockIdx.x * 1024 + t * 4;
    int s = 0;
#pragma unroll
    for (int j = 0; j < 4; j++) { int i = base + j; if (i < n) s += cnt[i]; }
    sd[t] = s; __syncthreads();
    for (int off = 128; off > 0; off >>= 1) {
        if (t < off) sd[t] += sd[t + off];
        __syncthreads();
    }
    if (t == 0) csum[blockIdx.x] = sd[0];
}

// parallel exclusive scan over up to 256 chunk sums (NCHUNK=98 here), 1 block
__global__ void k_scanB(int* csum, int* offsets, int nchunk, int n) {
    __shared__ int sd[256];
    int t = threadIdx.x;
    int v = (t < nchunk) ? csum[t] : 0;
    sd[t] = v; __syncthreads();
    for (int off = 1; off < 256; off <<= 1) {
        int u = (t >= off) ? sd[t - off] : 0;
        __syncthreads();
        sd[t] += u;
        __syncthreads();
    }
    if (t < nchunk) csum[t] = sd[t] - v;   // exclusive prefix
    if (t == 0) offsets[n] = sd[255];      // total = E + N
}

// scanC + node_init fused: writes offsets, dinv, cursor, and the self-loop entry.
__global__ void k_scanC(const int* __restrict__ cnt, const int* __restrict__ csum,
                        int* offsets, int* cursor, float* dinv,
                        int* adj_src, float* adj_norm, int n) {
    __shared__ int sd[256];
    int t = threadIdx.x;
    int base = blockIdx.x * 1024 + t * 4;
    int c[4]; int s = 0;
#pragma unroll
    for (int j = 0; j < 4; j++) {
        c[j] = (base + j < n) ? cnt[base + j] : 0;
        s += c[j];
    }
    sd[t] = s; __syncthreads();
    // inclusive Hillis-Steele over 256 thread sums
    for (int off = 1; off < 256; off <<= 1) {
        int v = (t >= off) ? sd[t - off] : 0;
        __syncthreads();
        sd[t] += v;
        __syncthreads();
    }
    int run = sd[t] - s + csum[blockIdx.x];  // exclusive prefix + chunk base
#pragma unroll
    for (int j = 0; j < 4; j++) {
        int i = base + j;
        if (i < n) {
            offsets[i] = run;
            float di = rsqrtf((float)c[j]);   // deg >= 1 (self-loop)
            dinv[i] = di;
            cursor[i] = run + 1;
            adj_src[run] = i;                 // self-loop entry first
            adj_norm[run] = di * di;
        }
        run += c[j];
    }
}

__global__ void k_fill_edges(const int* __restrict__ ei, int* cursor,
                             const float* __restrict__ dinv,
                             int* adj_src, float* adj_norm, int E) {
    int e = blockIdx.x * blockDim.x + threadIdx.x;
    if (e >= E) return;
    int s = ei[e];
    int d = ei[E + e];
    int pos = atomicAdd(&cursor[d], 1);
    adj_src[pos] = s;
    adj_norm[pos] = dinv[s] * dinv[d];
}

// ---------- fused layer: agg (pull) -> LDS -> GEMM + bias + relu ----------
// 512 threads (8 waves), 32-node tile. LDS: W 64KB + Xs 16KB = 80KB => 2 blocks/CU.
// Agg: each wave aggregates 4 nodes; per body ONE float4 gather covering 2 edges
// (wave quarters: q>>1 = edge parity, q&1 = feature half), shfl_xor(32) combine.
// GEMM: each thread 2 rows x 4 cols from LDS W + Xs.

__global__ __launch_bounds__(512, 2) void k_layer(const float* __restrict__ x,
                                                  const int* __restrict__ offsets,
                                                  const int* __restrict__ adj_src,
                                                  const float* __restrict__ adj_norm,
                                                  const float* __restrict__ W,
                                                  const float* __restrict__ bias,
                                                  float* __restrict__ out, int n) {
    __shared__ float Wl[HID * HID];   // 64 KB, [k][f]
    __shared__ float Xs[32 * HID];    // 16 KB, [row][k]
    int t = threadIdx.x;

    {   // stage W once per block (4096 float4s / 512 threads = 8 each)
        const float4* Wg = (const float4*)W;
        float4* Wd = (float4*)Wl;
#pragma unroll
        for (int i = 0; i < 8; i++) Wd[t + i * 512] = Wg[t + i * 512];
    }

    int wave = t >> 6;               // 0..7
    int lane = t & 63;
    int q    = lane >> 4;            // quarter 0..3
    int ql   = lane & 15;
    int f4   = (q & 1) * 16 + ql;    // float4 index within row, [0,32)
    int epar = q >> 1;               // edge-slot parity 0/1
    int tx = t & 31;                 // feat group: f0 = tx*4
    int ty = t >> 5;                 // row group: rows ty*2, ty*2+1  (0..15)
    int ntiles = n / 32;             // 100000 % 32 == 0

    for (int tile = blockIdx.x; tile < ntiles; tile += gridDim.x) {
        __syncthreads();   // protect Xs reuse (and W on first iter)

        // ---- agg phase: wave w aggregates tile rows w*4 .. w*4+3 ----
        for (int i = 0; i < 4; i++) {
            int r = wave * 4 + i;
            int node = tile * 32 + r;
            int beg = offsets[node];
            int end = offsets[node + 1];
            float4 acc = {0.f, 0.f, 0.f, 0.f};
#pragma unroll 2
            for (int e = beg; e < end; e += 2) {
                int me = e + epar;
                int mc = me < end ? me : end - 1;          // clamp -> valid load
                int s  = adj_src[mc];
                float w = me < end ? adj_norm[mc] : 0.f;   // mask odd tail
                float4 v = ((const float4*)(x + (size_t)s * HID))[f4];
                acc.x += w * v.x;
                acc.y += w * v.y;
                acc.z += w * v.z;
                acc.w += w * v.w;
            }
            acc.x += __shfl_xor(acc.x, 32);
            acc.y += __shfl_xor(acc.y, 32);
            acc.z += __shfl_xor(acc.z, 32);
            acc.w += __shfl_xor(acc.w, 32);
            if (lane < 32)
                ((float4*)(Xs + r * HID))[lane] = acc;
        }
        __syncthreads();

        // ---- gemm phase: out[tile rows] = relu(Xs @ W + b) ----
        float a00 = 0.f, a01 = 0.f, a02 = 0.f, a03 = 0.f;
        float a10 = 0.f, a11 = 0.f, a12 = 0.f, a13 = 0.f;
#pragma unroll 8
        for (int k = 0; k < HID; k++) {
            float4 wv = ((const float4*)(Wl + k * HID))[tx];
            float x0 = Xs[(ty * 2) * HID + k];
            float x1 = Xs[(ty * 2 + 1) * HID + k];
            a00 += x0 * wv.x; a01 += x0 * wv.y; a02 += x0 * wv.z; a03 += x0 * wv.w;
            a10 += x1 * wv.x; a11 += x1 * wv.y; a12 += x1 * wv.z; a13 += x1 * wv.w;
        }
        float4 bb = ((const float4*)bias)[tx];
        float4 o0, o1;
        o0.x = fmaxf(a00 + bb.x, 0.f); o0.y = fmaxf(a01 + bb.y, 0.f);
        o0.z = fmaxf(a02 + bb.z, 0.f); o0.w = fmaxf(a03 + bb.w, 0.f);
        o1.x = fmaxf(a10 + bb.x, 0.f); o1.y = fmaxf(a11 + bb.y, 0.f);
        o1.z = fmaxf(a12 + bb.z, 0.f); o1.w = fmaxf(a13 + bb.w, 0.f);
        size_t row0 = (size_t)tile * 32 + ty * 2;
        ((float4*)(out + row0 * HID))[tx] = o0;
        ((float4*)(out + (row0 + 1) * HID))[tx] = o1;
    }
}

// ---------- launch ----------

extern "C" void kernel_launch(void* const* d_in, const int* in_sizes, int n_in,
                              void* d_out, int out_size, void* d_ws, size_t ws_size,
                              hipStream_t stream) {
    const int* ei = (const int*)d_in[0];          // (2, E) int32
    const float* emb = (const float*)d_in[1];     // (N, 128)
    const float* Ws = (const float*)d_in[2];      // (3, 128, 128)
    const float* bs = (const float*)d_in[3];      // (3, 128)

    const int E = in_sizes[0] / 2;                // 600000
    const int N = in_sizes[1] / HID;              // 100000
    const int NL = in_sizes[3] / HID;             // 3
    const int TOT = E + N;

    // workspace carve-up (256B aligned)
    char* p = (char*)d_ws;
    auto carve = [&](size_t bytes) {
        char* r = p;
        p += (bytes + 255) & ~(size_t)255;
        return (void*)r;
    };
    int*   cnt      = (int*)  carve((size_t)N * 4);
    int*   offsets  = (int*)  carve((size_t)(N + 1) * 4);
    int*   cursor   = (int*)  carve((size_t)N * 4);
    float* dinv     = (float*)carve((size_t)N * 4);
    int*   csum     = (int*)  carve(1024 * 4);
    int*   adj_src  = (int*)  carve((size_t)TOT * 4);
    float* adj_norm = (float*)carve((size_t)TOT * 4);
    float* xbufA    = (float*)carve((size_t)N * HID * 4);
    float* xbufB    = (float*)d_out;   // final layer lands here

    const int NCHUNK = (N + 1023) / 1024;   // 98 <= 256 (scanB capacity)

    k_init_cnt<<<(N + 255) / 256, 256, 0, stream>>>(cnt, N);
    k_count_edges<<<(E + 255) / 256, 256, 0, stream>>>(ei, cnt, E);
    k_scanA<<<NCHUNK, 256, 0, stream>>>(cnt, csum, N);
    k_scanB<<<1, 256, 0, stream>>>(csum, offsets, NCHUNK, N);
    k_scanC<<<NCHUNK, 256, 0, stream>>>(cnt, csum, offsets, cursor, dinv,
                                        adj_src, adj_norm, N);
    k_fill_edges<<<(E + 255) / 256, 256, 0, stream>>>(ei, cursor, dinv,
                                                      adj_src, adj_norm, E);

    // layer l: in -> out.  0: emb->A, 1: A->B(d_out)... ensure LAST lands in d_out.
    // 3 layers: emb -> A -> A2? Use ping-pong emb->A, A->xbufB? xbufB=d_out used as
    // scratch for layer-1 output, then layer-2 reads d_out and writes... must END in
    // d_out: emb->A (l0), A->B (l1, B=d_out)?? l2 would be B->? Need a third: reuse A.
    // Sequence: l0: emb->A, l1: A->B(d_out) is WRONG end. Do: l0: emb->B(d_out),
    // l1: B->A, l2: A->B(d_out). d_out is restored/poisoned per call; safe as scratch.
    const float* x = emb;
    for (int l = 0; l < NL; l++) {
        float* o = (l % 2 == 0) ? xbufB : xbufA;   // l0->d_out, l1->A, l2->d_out
        k_layer<<<512, 512, 0, stream>>>(x, offsets, adj_src, adj_norm,
                                         Ws + (size_t)l * HID * HID,
                                         bs + (size_t)l * HID, o, N);
        x = o;
    }
}